// Round 1
// baseline (78.601 us; speedup 1.0000x reference)
//
#include <hip/hip_runtime.h>

constexpr int M      = 49;    // filter order
constexpr int TAPS   = 50;    // M+1
constexpr int P      = 80;    // frame period
constexpr int BLOCK  = 256;
constexpr int NFR    = 6;     // max coeff frames touched by one block (4 span + 1 straddle + 1 interp)
constexpr int FSTRIDE = 52;   // padded LDS frame stride (floats), keeps 16B alignment

__global__ __launch_bounds__(BLOCK) void azdf_kernel(
    const float* __restrict__ x, const float* __restrict__ b,
    float* __restrict__ y, int T, int N) {
  __shared__ float xs[BLOCK + M + 3];
  __shared__ float bs[NFR * FSTRIDE];

  const int batch = blockIdx.y;
  const int t0 = blockIdx.x * BLOCK;
  const int tid = threadIdx.x;
  const float* xb = x + (size_t)batch * T;
  const float* bb = b + (size_t)batch * N * TAPS;

  // stage x[t0-M .. t0+BLOCK-1] (zero-pad left edge, guard right edge)
  for (int i = tid; i < BLOCK + M; i += BLOCK) {
    int xi = t0 - M + i;
    xs[i] = (xi >= 0 && xi < T) ? xb[xi] : 0.0f;
  }

  // stage coeff frames n_first .. n_first+NFR-1, clamped to N-1
  const int n_first = t0 / P;
  for (int i = tid; i < NFR * TAPS; i += BLOCK) {
    int f = i / TAPS;
    int k = i - f * TAPS;
    int n = n_first + f;
    if (n > N - 1) n = N - 1;
    bs[f * FSTRIDE + k] = bb[(size_t)n * TAPS + k];
  }
  __syncthreads();

  const int t = t0 + tid;
  if (t < T) {
    const int n = t / P;
    const float w = (float)(t - n * P) * (1.0f / (float)P);
    const float* c0 = &bs[(n - n_first) * FSTRIDE];  // b[n]   (flipped ref == lag-indexed)
    const float* c1 = c0 + FSTRIDE;                  // b[min(n+1, N-1)] (clamp done at load)
    float s0 = 0.0f, s1 = 0.0f;
#pragma unroll
    for (int k = 0; k < TAPS; ++k) {
      float xv = xs[tid + M - k];
      s0 = fmaf(xv, c0[k], s0);
      s1 = fmaf(xv, c1[k], s1);
    }
    y[(size_t)batch * T + t] = (1.0f - w) * s0 + w * s1;
  }
}

extern "C" void kernel_launch(void* const* d_in, const int* in_sizes, int n_in,
                              void* d_out, int out_size, void* d_ws, size_t ws_size,
                              hipStream_t stream) {
  const float* x = (const float*)d_in[0];
  const float* b = (const float*)d_in[1];
  float* y = (float*)d_out;

  const int B = 8;                              // fixed by setup_inputs
  const int N = in_sizes[1] / (B * TAPS);       // 3000
  const int T = N * P;                          // 240000

  dim3 grid((T + BLOCK - 1) / BLOCK, B);
  azdf_kernel<<<grid, BLOCK, 0, stream>>>(x, b, y, T, N);
}

// Round 2
// 75.441 us; speedup vs baseline: 1.0419x; 1.0419x over previous
//
#include <hip/hip_runtime.h>

constexpr int M      = 49;    // filter order
constexpr int TAPS   = 50;    // M+1
constexpr int P      = 80;    // frame period
constexpr int BLOCK  = 256;
constexpr int R      = 8;     // outputs per thread; 80 % 8 == 0 -> one coeff frame per thread
constexpr int TILE   = BLOCK * R;   // 2048 outputs per block
constexpr int NFR    = 28;    // frames touched by a block: <=26 span + 1 interp + slack
constexpr int FSTRIDE = 52;   // padded LDS frame stride (floats); 208 B = 16B-aligned

__global__ __launch_bounds__(BLOCK) void azdf_kernel(
    const float* __restrict__ x, const float* __restrict__ b,
    float* __restrict__ y, int T, int N) {
  __shared__ float xs[TILE + M + 15];   // +15: zero pad for b128 over-read
  __shared__ float bs[NFR * FSTRIDE];

  const int batch = blockIdx.y;
  const int t0 = blockIdx.x * TILE;
  const int tid = threadIdx.x;
  const float* xb = x + (size_t)batch * T;
  const float* bb = b + (size_t)batch * N * TAPS;

  // stage x[t0-M .. t0+TILE-1] (zero-pad edges)
  for (int i = tid; i < TILE + M; i += BLOCK) {
    int xi = t0 - M + i;
    xs[i] = (xi >= 0 && xi < T) ? xb[xi] : 0.0f;
  }
  if (tid < 15) xs[TILE + M + tid] = 0.0f;

  // stage coeff frames n_first .. n_first+NFR-1 (clamped to N-1)
  const int n_first = t0 / P;
  for (int i = tid; i < NFR * TAPS; i += BLOCK) {
    int f = i / TAPS;
    int k = i - f * TAPS;
    int n = n_first + f;
    if (n > N - 1) n = N - 1;
    bs[f * FSTRIDE + k] = bb[(size_t)n * TAPS + k];
  }
  __syncthreads();

  const int t_base = t0 + tid * R;
  if (t_base >= T) return;

  // 57-float x window -> registers, 15 x ds_read_b128 (base = tid*32B, aligned)
  float xr[60];
#pragma unroll
  for (int j = 0; j < 15; ++j) {
    float4 v = *(const float4*)&xs[tid * R + 4 * j];
    xr[4 * j + 0] = v.x; xr[4 * j + 1] = v.y;
    xr[4 * j + 2] = v.z; xr[4 * j + 3] = v.w;
  }

  const int n = t_base / P;           // same frame for all R outputs (80 % 8 == 0)
  const float* c0 = &bs[(n - n_first) * FSTRIDE];
  const float* c1 = c0 + FSTRIDE;     // clamp already applied at staging

  float s0[R], s1[R];
#pragma unroll
  for (int r = 0; r < R; ++r) { s0[r] = 0.0f; s1[r] = 0.0f; }

  // k in chunks of 4, coeffs via 16B-aligned b128 reads
#pragma unroll
  for (int kc = 0; kc < 48; kc += 4) {
    float4 a0 = *(const float4*)&c0[kc];
    float4 a1 = *(const float4*)&c1[kc];
    const float av0[4] = {a0.x, a0.y, a0.z, a0.w};
    const float av1[4] = {a1.x, a1.y, a1.z, a1.w};
#pragma unroll
    for (int kk = 0; kk < 4; ++kk) {
      const int k = kc + kk;
#pragma unroll
      for (int r = 0; r < R; ++r) {
        float xv = xr[M + r - k];
        s0[r] = fmaf(xv, av0[kk], s0[r]);
        s1[r] = fmaf(xv, av1[kk], s1[r]);
      }
    }
  }
  { // tail k = 48, 49 (8B-aligned b64 reads)
    float2 a0 = *(const float2*)&c0[48];
    float2 a1 = *(const float2*)&c1[48];
#pragma unroll
    for (int r = 0; r < R; ++r) {
      float xv = xr[M + r - 48];
      s0[r] = fmaf(xv, a0.x, s0[r]);
      s1[r] = fmaf(xv, a1.x, s1[r]);
    }
#pragma unroll
    for (int r = 0; r < R; ++r) {
      float xv = xr[M + r - 49];
      s0[r] = fmaf(xv, a0.y, s0[r]);
      s1[r] = fmaf(xv, a1.y, s1[r]);
    }
  }

  const int phase = t_base - n * P;
  float out[R];
#pragma unroll
  for (int r = 0; r < R; ++r) {
    float w = (float)(phase + r) * (1.0f / (float)P);
    out[r] = (1.0f - w) * s0[r] + w * s1[r];
  }

  float* yp = y + (size_t)batch * T + t_base;
  if (t_base + R <= T) {
    *(float4*)(yp + 0) = make_float4(out[0], out[1], out[2], out[3]);
    *(float4*)(yp + 4) = make_float4(out[4], out[5], out[6], out[7]);
  } else {
    for (int r = 0; r < R && t_base + r < T; ++r) yp[r] = out[r];
  }
}

extern "C" void kernel_launch(void* const* d_in, const int* in_sizes, int n_in,
                              void* d_out, int out_size, void* d_ws, size_t ws_size,
                              hipStream_t stream) {
  const float* x = (const float*)d_in[0];
  const float* b = (const float*)d_in[1];
  float* y = (float*)d_out;

  const int B = 8;                         // fixed by setup_inputs
  const int N = in_sizes[1] / (B * TAPS);  // 3000
  const int T = N * P;                     // 240000

  dim3 grid((T + TILE - 1) / TILE, B);
  azdf_kernel<<<grid, BLOCK, 0, stream>>>(x, b, y, T, N);
}

// Round 4
// 71.458 us; speedup vs baseline: 1.1000x; 1.0557x over previous
//
#include <hip/hip_runtime.h>

constexpr int M      = 49;    // filter order
constexpr int TAPS   = 50;    // M+1
constexpr int P      = 80;    // frame period
constexpr int BLOCK  = 256;
constexpr int R      = 8;     // outputs per thread; 8 | 80 -> one coeff frame per thread
constexpr int WFR    = 9;     // coeff frame slots per wave: 512 outputs can span
                              // n_first..n_first+7, +1 interp partner -> 9 slots
constexpr int FSTRIDE = 52;   // padded LDS frame stride (floats)
constexpr int WAVES  = BLOCK / 64;

// No __syncthreads: each wave stages its own coefficient frames into a
// wave-private LDS region (intra-wave ds ordering via compiler waitcnt),
// and reads its x-window directly from global with aligned float4.
__global__ __launch_bounds__(BLOCK) void azdf_kernel(
    const float* __restrict__ x, const float* __restrict__ b,
    float* __restrict__ y, int T, int N) {
  __shared__ float bs[WAVES * WFR * FSTRIDE];

  const int batch = blockIdx.y;
  const int tid  = threadIdx.x;
  const int wave = tid >> 6;
  const int lane = tid & 63;
  const float* xb = x + (size_t)batch * T;
  const float* bb = b + (size_t)batch * N * TAPS;

  // first output t of this wave; 512 consecutive outputs per wave
  const int w0 = (blockIdx.x * BLOCK + wave * 64) * R;
  const int n_first = w0 / P;
  float* wbs = &bs[wave * WFR * FSTRIDE];

  // wave-cooperative staging of frames n_first .. n_first+8 (clamped to N-1)
  for (int i = lane; i < WFR * TAPS; i += 64) {
    int f = i / TAPS;
    int k = i - f * TAPS;
    int n = n_first + f;
    if (n > N - 1) n = N - 1;
    wbs[f * FSTRIDE + k] = bb[(size_t)n * TAPS + k];
  }

  const int t_base = w0 + lane * R;
  if (t_base >= T) return;   // after staging: whole wave contributed

  // x[t_base-52 .. t_base+7] -> 60 regs; base is 16B-aligned (t_base % 8 == 0)
  float xr[60];
  if (t_base >= 52) {
    const float* xp = xb + t_base - 52;
#pragma unroll
    for (int j = 0; j < 15; ++j) {
      float4 v = *(const float4*)(xp + 4 * j);
      xr[4*j+0] = v.x; xr[4*j+1] = v.y; xr[4*j+2] = v.z; xr[4*j+3] = v.w;
    }
  } else {  // left edge: first 7 threads of each batch only
#pragma unroll
    for (int i = 0; i < 60; ++i) {
      int xi = t_base - 52 + i;
      xr[i] = (xi >= 0) ? xb[xi] : 0.0f;
    }
  }

  const int n = t_base / P;                     // same frame for all R outputs
  const float* c0 = &wbs[(n - n_first) * FSTRIDE];
  const float* c1 = c0 + FSTRIDE;               // clamp applied at staging

  float s0[R], s1[R];
#pragma unroll
  for (int r = 0; r < R; ++r) { s0[r] = 0.0f; s1[r] = 0.0f; }

  // x[t_base + r - k] == xr[52 + r - k]
#pragma unroll
  for (int kc = 0; kc < 48; kc += 4) {
    float4 a0 = *(const float4*)&c0[kc];
    float4 a1 = *(const float4*)&c1[kc];
    const float av0[4] = {a0.x, a0.y, a0.z, a0.w};
    const float av1[4] = {a1.x, a1.y, a1.z, a1.w};
#pragma unroll
    for (int kk = 0; kk < 4; ++kk) {
      const int k = kc + kk;
#pragma unroll
      for (int r = 0; r < R; ++r) {
        float xv = xr[52 + r - k];
        s0[r] = fmaf(xv, av0[kk], s0[r]);
        s1[r] = fmaf(xv, av1[kk], s1[r]);
      }
    }
  }
  {  // tail k = 48, 49
    float2 a0 = *(const float2*)&c0[48];
    float2 a1 = *(const float2*)&c1[48];
#pragma unroll
    for (int r = 0; r < R; ++r) {
      float xv = xr[52 + r - 48];
      s0[r] = fmaf(xv, a0.x, s0[r]);
      s1[r] = fmaf(xv, a1.x, s1[r]);
    }
#pragma unroll
    for (int r = 0; r < R; ++r) {
      float xv = xr[52 + r - 49];
      s0[r] = fmaf(xv, a0.y, s0[r]);
      s1[r] = fmaf(xv, a1.y, s1[r]);
    }
  }

  const int phase = t_base - n * P;
  float out[R];
#pragma unroll
  for (int r = 0; r < R; ++r) {
    float w = (float)(phase + r) * (1.0f / (float)P);
    out[r] = (1.0f - w) * s0[r] + w * s1[r];
  }

  float* yp = y + (size_t)batch * T + t_base;   // 32B-aligned, T % 8 == 0
  *(float4*)(yp + 0) = make_float4(out[0], out[1], out[2], out[3]);
  *(float4*)(yp + 4) = make_float4(out[4], out[5], out[6], out[7]);
}

extern "C" void kernel_launch(void* const* d_in, const int* in_sizes, int n_in,
                              void* d_out, int out_size, void* d_ws, size_t ws_size,
                              hipStream_t stream) {
  const float* x = (const float*)d_in[0];
  const float* b = (const float*)d_in[1];
  float* y = (float*)d_out;

  const int B = 8;                         // fixed by setup_inputs
  const int N = in_sizes[1] / (B * TAPS);  // 3000
  const int T = N * P;                     // 240000

  const int threads_per_batch = T / R;     // 30000
  dim3 grid((threads_per_batch + BLOCK - 1) / BLOCK, B);
  azdf_kernel<<<grid, BLOCK, 0, stream>>>(x, b, y, T, N);
}